// Round 1
// baseline (256.516 us; speedup 1.0000x reference)
//
#include <hip/hip_runtime.h>
#include <hip/hip_bf16.h>

typedef __attribute__((ext_vector_type(4))) float f32x4;
typedef __attribute__((ext_vector_type(8))) short bf16x8;

#define DEV __device__ __forceinline__

DEV unsigned short f2bf(float f) {
  union { float f; unsigned int u; } v; v.f = f;
  unsigned int r = v.u + 0x7fffu + ((v.u >> 16) & 1u);
  return (unsigned short)(r >> 16);
}

DEV float gelu_exact(float v) {
  return 0.5f * v * (1.0f + erff(v * 0.70710678118654752f));
}

// window token row -> natural (b,t,h,w) flat token index (handles roll both ways)
DEV size_t winmap(int row) {
  int wIdx = row >> 7, n = row & 127;
  int b = wIdx >> 8, widx = wIdx & 255;
  int t = (((widx >> 6) * 2 + (n >> 6)) + 1) & 7;
  int h = ((((widx >> 3) & 7) * 8 + ((n >> 3) & 7)) + 4) & 63;
  int w = (((widx & 7) * 8 + (n & 7)) + 4) & 63;
  return (size_t)(((b * 8 + t) * 64 + h) * 64 + w);
}

DEV void gload16(const unsigned short* g, unsigned short* lds) {
  __builtin_amdgcn_global_load_lds(
      (const __attribute__((address_space(1))) unsigned int*)g,
      (__attribute__((address_space(3))) unsigned int*)lds, 16, 0, 0);
}

// ---------------- prep: cast weights to bf16, build per-head rel-pos bias ----------------
__global__ __launch_bounds__(256) void k_prep(
    const float* __restrict__ qkv_w, const float* __restrict__ proj_w,
    const float* __restrict__ fc1_w, const float* __restrict__ fc2_w,
    const float* __restrict__ rpb_t, const int* __restrict__ rpb_i,
    unsigned short* __restrict__ wq, unsigned short* __restrict__ wp,
    unsigned short* __restrict__ w1, unsigned short* __restrict__ w2,
    float* __restrict__ b6) {
  int i = blockIdx.x * 256 + threadIdx.x;
  if (i < 110592) wq[i] = f2bf(qkv_w[i]);
  if (i < 36864)  wp[i] = f2bf(proj_w[i]);
  if (i < 147456) { w1[i] = f2bf(fc1_w[i]); w2[i] = f2bf(fc2_w[i]); }
  if (i < 16384) {
    int idx = rpb_i[i];
    #pragma unroll
    for (int h = 0; h < 6; ++h) b6[h * 16384 + i] = rpb_t[idx * 6 + h];
  }
}

// ---------------- gather: roll + window-partition, f32 -> bf16 ----------------
__global__ __launch_bounds__(256) void k_gather(const float* __restrict__ x,
                                                unsigned short* __restrict__ xw) {
  int i = blockIdx.x * 256 + threadIdx.x;   // over 65536*48 float4s
  int row = i / 48;
  int c4 = (i - row * 48) * 4;
  float4 v = *(const float4*)(x + winmap(row) * 192 + c4);
  ushort4 o;
  o.x = f2bf(v.x); o.y = f2bf(v.y); o.z = f2bf(v.z); o.w = f2bf(v.w);
  *(ushort4*)(xw + (size_t)row * 192 + c4) = o;
}

// ---------------- generic 128x64 tile bf16 GEMM: C = A @ B^T + bias, epilogues ----------------
// A: M x K bf16 (lda = K), B: N x K bf16 (row stride K)
enum { EPI_BF16 = 0, EPI_GELU = 1, EPI_PROJ = 2, EPI_FC2 = 3 };

template <int EPI>
__global__ __launch_bounds__(256) void gemm_bt(
    const unsigned short* __restrict__ A, const unsigned short* __restrict__ Bm,
    const float* __restrict__ bias, unsigned short* __restrict__ outb,
    float* __restrict__ outf, const float* __restrict__ xres,
    int M, int N, int K) {
  __shared__ unsigned short As[128 * 64];
  __shared__ unsigned short Bs[64 * 64];
  const int tid = threadIdx.x;
  const int wave = tid >> 6, lane = tid & 63;
  const int nt = blockIdx.x, mt = blockIdx.y;
  const int m0 = mt * 128, n0 = nt * 64;
  const int wr = wave >> 1, wc = wave & 1;
  const int l8 = lane >> 3, s8 = lane & 7;
  f32x4 acc[4][2] = {};

  for (int kt = 0; kt < K; kt += 64) {
    __syncthreads();
    // stage A: 16 chunks x 1024B (8 rows of 128B). dest linear, source inverse-swizzled.
    #pragma unroll
    for (int i = 0; i < 4; ++i) {
      int c = wave * 4 + i;
      int row = c * 8 + l8;
      int slot = s8 ^ (row & 7);
      gload16(A + (size_t)(m0 + row) * K + kt + slot * 8, As + c * 512);
    }
    // stage B: 8 chunks
    #pragma unroll
    for (int i = 0; i < 2; ++i) {
      int c = wave * 2 + i;
      int row = c * 8 + l8;
      int slot = s8 ^ (row & 7);
      gload16(Bm + (size_t)(n0 + row) * K + kt + slot * 8, Bs + c * 512);
    }
    __syncthreads();

    #pragma unroll
    for (int kk = 0; kk < 2; ++kk) {
      bf16x8 af[4], bf[2];
      #pragma unroll
      for (int mi = 0; mi < 4; ++mi) {
        int row = wr * 64 + mi * 16 + (lane & 15);
        int slot = (kk * 4 + (lane >> 4)) ^ (row & 7);
        af[mi] = *(const bf16x8*)(As + row * 64 + slot * 8);
      }
      #pragma unroll
      for (int ni = 0; ni < 2; ++ni) {
        int row = wc * 32 + ni * 16 + (lane & 15);
        int slot = (kk * 4 + (lane >> 4)) ^ (row & 7);
        bf[ni] = *(const bf16x8*)(Bs + row * 64 + slot * 8);
      }
      #pragma unroll
      for (int mi = 0; mi < 4; ++mi)
        #pragma unroll
        for (int ni = 0; ni < 2; ++ni)
          acc[mi][ni] = __builtin_amdgcn_mfma_f32_16x16x32_bf16(af[mi], bf[ni], acc[mi][ni], 0, 0, 0);
    }
  }

  // epilogue. C/D layout: col = lane&15, row = (lane>>4)*4 + j
  #pragma unroll
  for (int ni = 0; ni < 2; ++ni) {
    int col = n0 + wc * 32 + ni * 16 + (lane & 15);
    float bb = bias[col];
    #pragma unroll
    for (int mi = 0; mi < 4; ++mi) {
      int rbase = m0 + wr * 64 + mi * 16 + ((lane >> 4) << 2);
      #pragma unroll
      for (int j = 0; j < 4; ++j) {
        int row = rbase + j;
        float v = acc[mi][ni][j] + bb;
        if (EPI == EPI_BF16) {
          outb[(size_t)row * N + col] = f2bf(v);
        } else if (EPI == EPI_GELU) {
          outb[(size_t)row * N + col] = f2bf(gelu_exact(v));
        } else if (EPI == EPI_PROJ) {
          size_t flat = winmap(row) * 192 + col;
          outb[flat] = f2bf(v + xres[flat]);        // y = z + x (bf16 for MLP A)
        } else {                                     // EPI_FC2
          size_t idx = (size_t)row * N + col;
          outf[idx] = xres[idx] + v;                 // out = x + mlp
        }
      }
    }
  }
}

// ---------------- attention: one block per (window, head) ----------------
__global__ __launch_bounds__(256) void k_attn(const unsigned short* __restrict__ qkv,
                                              const float* __restrict__ mask,
                                              const float* __restrict__ bias6,
                                              unsigned short* __restrict__ attn_out) {
  __shared__ unsigned short Kl[128 * 40];   // [128][32] pad->40 (conflict-free frag reads)
  __shared__ unsigned short Vt[32 * 136];   // V^T [32][128] pad->136
  __shared__ unsigned short Pl[128 * 136];  // P [128][128] pad->136
  const int hd = blockIdx.x;
  const int wIdx = blockIdx.y;
  const int tid = threadIdx.x;
  const int wave = tid >> 6, lane = tid & 63;
  const int widx = wIdx & 255;
  const size_t qbase = (size_t)wIdx * 73728;   // *128*576

  // stage K rows (128 x 32 bf16), padded row stride 40
  #pragma unroll
  for (int r = 0; r < 2; ++r) {
    int idx = r * 256 + tid;
    int row = idx >> 2, slot = idx & 3;
    *(bf16x8*)(Kl + row * 40 + slot * 8) =
        *(const bf16x8*)(qkv + qbase + (size_t)row * 576 + 192 + hd * 32 + slot * 8);
  }
  // stage V transposed: Vt[d][m]
  if (tid < 128) {
    #pragma unroll
    for (int slot = 0; slot < 4; ++slot) {
      bf16x8 v = *(const bf16x8*)(qkv + qbase + (size_t)tid * 576 + 384 + hd * 32 + slot * 8);
      #pragma unroll
      for (int j = 0; j < 8; ++j)
        Vt[(slot * 8 + j) * 136 + tid] = (unsigned short)v[j];
    }
  }
  // Q fragments straight from global (A layout: row = lane&15, k = (lane>>4)*8..+8)
  bf16x8 qf[2];
  #pragma unroll
  for (int tr = 0; tr < 2; ++tr)
    qf[tr] = *(const bf16x8*)(qkv + qbase +
                              (size_t)(wave * 32 + tr * 16 + (lane & 15)) * 576 +
                              hd * 32 + (lane >> 4) * 8);
  __syncthreads();

  // S = Q @ K^T  (wave covers rows wave*32..+31, all 128 cols)
  f32x4 s[2][8];
  #pragma unroll
  for (int tc = 0; tc < 8; ++tc) {
    bf16x8 kf = *(const bf16x8*)(Kl + (tc * 16 + (lane & 15)) * 40 + (lane >> 4) * 8);
    #pragma unroll
    for (int tr = 0; tr < 2; ++tr) {
      f32x4 z = {0.f, 0.f, 0.f, 0.f};
      s[tr][tc] = __builtin_amdgcn_mfma_f32_16x16x32_bf16(qf[tr], kf, z, 0, 0, 0);
    }
  }

  // scale + bias + mask + row softmax (16-lane shfl groups), write P (bf16) to LDS
  const float scale = 0.17677669529663687f;   // 32^-0.5
  float rsum[2][4];
  #pragma unroll
  for (int tr = 0; tr < 2; ++tr) {
    #pragma unroll
    for (int j = 0; j < 4; ++j) {
      int row = wave * 32 + tr * 16 + ((lane >> 4) << 2) + j;
      const float* bp = bias6 + hd * 16384 + row * 128;
      const float* mp = mask + (size_t)widx * 16384 + row * 128;
      float mx = -1e30f;
      #pragma unroll
      for (int tc = 0; tc < 8; ++tc) {
        int col = tc * 16 + (lane & 15);
        float v = s[tr][tc][j] * scale + bp[col] + mp[col];
        s[tr][tc][j] = v;
        mx = fmaxf(mx, v);
      }
      #pragma unroll
      for (int d = 1; d < 16; d <<= 1) mx = fmaxf(mx, __shfl_xor(mx, d));
      float sum = 0.f;
      #pragma unroll
      for (int tc = 0; tc < 8; ++tc) {
        float p = __expf(s[tr][tc][j] - mx);
        s[tr][tc][j] = p;
        sum += p;
      }
      #pragma unroll
      for (int d = 1; d < 16; d <<= 1) sum += __shfl_xor(sum, d);
      rsum[tr][j] = sum;
      #pragma unroll
      for (int tc = 0; tc < 8; ++tc)
        Pl[row * 136 + tc * 16 + (lane & 15)] = f2bf(s[tr][tc][j]);
    }
  }
  __syncthreads();

  // O = P @ V   (A frags from Pl, B frags from Vt)
  f32x4 o[2][2] = {};
  #pragma unroll
  for (int ks = 0; ks < 4; ++ks) {
    bf16x8 pa[2], vb[2];
    #pragma unroll
    for (int tr = 0; tr < 2; ++tr)
      pa[tr] = *(const bf16x8*)(Pl + (wave * 32 + tr * 16 + (lane & 15)) * 136 +
                                ks * 32 + (lane >> 4) * 8);
    #pragma unroll
    for (int nc = 0; nc < 2; ++nc)
      vb[nc] = *(const bf16x8*)(Vt + (nc * 16 + (lane & 15)) * 136 +
                                ks * 32 + (lane >> 4) * 8);
    #pragma unroll
    for (int tr = 0; tr < 2; ++tr)
      #pragma unroll
      for (int nc = 0; nc < 2; ++nc)
        o[tr][nc] = __builtin_amdgcn_mfma_f32_16x16x32_bf16(pa[tr], vb[nc], o[tr][nc], 0, 0, 0);
  }

  #pragma unroll
  for (int tr = 0; tr < 2; ++tr)
    #pragma unroll
    for (int nc = 0; nc < 2; ++nc)
      #pragma unroll
      for (int j = 0; j < 4; ++j) {
        int row = wave * 32 + tr * 16 + ((lane >> 4) << 2) + j;
        float v = o[tr][nc][j] * (1.0f / rsum[tr][j]);
        attn_out[((size_t)wIdx * 128 + row) * 192 + hd * 32 + nc * 16 + (lane & 15)] = f2bf(v);
      }
}

// ---------------- launch ----------------
extern "C" void kernel_launch(void* const* d_in, const int* in_sizes, int n_in,
                              void* d_out, int out_size, void* d_ws, size_t ws_size,
                              hipStream_t stream) {
  const float* x      = (const float*)d_in[0];
  const float* mask   = (const float*)d_in[1];
  const float* qkv_w  = (const float*)d_in[2];
  const float* qkv_b  = (const float*)d_in[3];
  const float* proj_w = (const float*)d_in[4];
  const float* proj_b = (const float*)d_in[5];
  const float* rpb_t  = (const float*)d_in[6];
  const int*   rpb_i  = (const int*)d_in[7];
  const float* fc1_w  = (const float*)d_in[8];
  const float* fc1_b  = (const float*)d_in[9];
  const float* fc2_w  = (const float*)d_in[10];
  const float* fc2_b  = (const float*)d_in[11];
  float* out = (float*)d_out;
  char* ws = (char*)d_ws;

  // workspace layout (peak ~127.2 MB, regions reused across phases)
  unsigned short* qkv = (unsigned short*)(ws + 0);          // 65536x576 bf16 (75.5 MB)
  unsigned short* att = (unsigned short*)(ws + 75497472);   // 65536x192 bf16 (25.2 MB)
  unsigned short* h1  = (unsigned short*)(ws + 0);          // 65536x768 bf16 (reuses qkv+att)
  unsigned short* xw  = (unsigned short*)(ws + 100663296);  // 65536x192 bf16
  unsigned short* ybf = (unsigned short*)(ws + 100663296);  // reuses xw slot
  unsigned short* wq  = (unsigned short*)(ws + 125829120);
  unsigned short* wp  = (unsigned short*)(ws + 126050304);
  unsigned short* w1  = (unsigned short*)(ws + 126124032);
  unsigned short* w2  = (unsigned short*)(ws + 126418944);
  float*          b6  = (float*)(ws + 126713856);

  k_prep<<<576, 256, 0, stream>>>(qkv_w, proj_w, fc1_w, fc2_w, rpb_t, rpb_i, wq, wp, w1, w2, b6);
  k_gather<<<12288, 256, 0, stream>>>(x, xw);
  gemm_bt<EPI_BF16><<<dim3(9, 512), 256, 0, stream>>>(xw, wq, qkv_b, qkv, nullptr, nullptr, 65536, 576, 192);
  k_attn<<<dim3(6, 512), 256, 0, stream>>>(qkv, mask, b6, att);
  gemm_bt<EPI_PROJ><<<dim3(3, 512), 256, 0, stream>>>(att, wp, proj_b, ybf, nullptr, x, 65536, 192, 192);
  gemm_bt<EPI_GELU><<<dim3(12, 512), 256, 0, stream>>>(ybf, w1, fc1_b, h1, nullptr, nullptr, 65536, 768, 192);
  gemm_bt<EPI_FC2><<<dim3(3, 512), 256, 0, stream>>>(h1, w2, fc2_b, nullptr, out, x, 65536, 192, 768);
}